// Round 14
// baseline (235.954 us; speedup 1.0000x reference)
//
#include <hip/hip_runtime.h>

// EntityClassify (R-GCN) — round 14.
// r13 post-mortem: 230us; fused1=112us top, Occ 29%, nothing saturated ->
// latency/sync-bound at 3 blocks/CU (48KB LDS). Fix: K-sliced staging BK=32
// (A 4KB + B 20KB = 24KB LDS) -> 4 blocks/CU (wave-capped), 2x co-residency.
// 8 stage+MFMA steps x 10 MFMA/wave (same 80 total). Swizzle adapted to 64B
// rows (conflict-free per 16-lane group). pull1/pull2 unchanged (isolate).

constexpr int NN = 100000, RR = 4, EE = 800000;
constexpr int RE = RR * EE;
constexpr int NBKT = (NN + 63) / 64;      // 1563 buckets of 64 dst nodes
constexpr int BCAP = 3072;                // per-bucket capacity (λ≈2046, σ≈45)
constexpr int NG1 = (NN + 63) / 64;       // 1563 gemm1 tiles (M=64)
constexpr int CHUNK = 8192;
constexpr int NB = (RE + CHUNK - 1) / CHUNK;  // 391 bin blocks
constexpr int EPT = CHUNK / 512;          // 16 edges per thread

typedef short bf16x8 __attribute__((ext_vector_type(8)));
typedef float f32x4 __attribute__((ext_vector_type(4)));

__device__ inline unsigned short f2bf(float f) {
  unsigned u = __float_as_uint(f);
  u += 0x7FFF + ((u >> 16) & 1);
  return (unsigned short)(u >> 16);
}
__device__ inline float bf2f(unsigned short s) {
  return __uint_as_float(((unsigned)s) << 16);
}

// ---- weights -> bf16 [n][k]: BT1 [320][256], BT2 [80][64] ----
__global__ __launch_bounds__(256) void prep_w_kernel(const float* __restrict__ W1,
                                                     const float* __restrict__ L1w,
                                                     const float* __restrict__ W2,
                                                     const float* __restrict__ L2w,
                                                     unsigned short* __restrict__ BT1,
                                                     unsigned short* __restrict__ BT2) {
  int idx = blockIdx.x * 256 + threadIdx.x;
  if (idx < 320 * 256) {
    int n = idx >> 8, k = idx & 255;
    float v = (n < 256) ? W1[((size_t)((n >> 6) * 256 + k)) * 64 + (n & 63)]
                        : L1w[(size_t)k * 64 + (n - 256)];
    BT1[idx] = f2bf(v);
  } else {
    int j = idx - 320 * 256;
    if (j < 80 * 64) {
      int n = j >> 6, k = j & 63;
      float v = (n < 64) ? W2[((size_t)((n >> 4) * 64 + k)) * 16 + (n & 15)]
                         : L2w[(size_t)k * 16 + (n - 64)];
      BT2[j] = f2bf(v);
    }
  }
}

// ---- fused1: bin blocks (every 5th) ∥ gemm1 blocks (BK=32, 24KB LDS) ----
__global__ __launch_bounds__(512) void fused1_kernel(const float* __restrict__ x,
                                                     const unsigned short* __restrict__ BT1,
                                                     const float* __restrict__ L1b,
                                                     const int* __restrict__ src,
                                                     const int* __restrict__ dst,
                                                     int* __restrict__ gcur,
                                                     int* __restrict__ binned,
                                                     unsigned short* __restrict__ hwcat,
                                                     unsigned short* __restrict__ h) {
  __shared__ char lds[64 * 64 + 320 * 64];   // 24576 B
  const int bid = blockIdx.x;
  const int t = threadIdx.x;
  const bool is_bin = (bid % 5 == 0) && (bid / 5 < NB);

  if (is_bin) {
    int* hist = (int*)lds;          // [NBKT]
    int* base = hist + NBKT;        // [NBKT]  (12.5 KB total, fits)
    for (int k = t; k < NBKT; k += 512) hist[k] = 0;
    __syncthreads();
    const int e0 = (bid / 5) * CHUNK + t;
    int dl[EPT], sl[EPT];
#pragma unroll
    for (int i = 0; i < EPT; ++i) {
      int fl = e0 + i * 512;
      dl[i] = -1;
      if (fl < RE) {
        dl[i] = dst[fl];
        sl[i] = src[fl];
        atomicAdd(&hist[dl[i] >> 6], 1);
      }
    }
    __syncthreads();
    for (int k = t; k < NBKT; k += 512) {
      int hv = hist[k];
      base[k] = hv ? atomicAdd(&gcur[k], hv) : 0;
      hist[k] = 0;
    }
    __syncthreads();
#pragma unroll
    for (int i = 0; i < EPT; ++i) {
      if (dl[i] < 0) continue;
      int fl = e0 + i * 512;
      int r = fl / EE;
      int b = dl[i] >> 6;
      int off = atomicAdd(&hist[b], 1);
      int p = base[b] + off;
      // entry: key = src*4+r (bits 0..18) | dstlo (bits 19..24)
      if (p < BCAP) binned[(size_t)b * BCAP + p] = (sl[i] << 2) | r | ((dl[i] & 63) << 19);
    }
    return;
  }

  // ---- gemm1 role: M-tile 64, N=320, K=256, BK=32 ----
  int nbins = (bid + 4) / 5;
  if (nbins > NB) nbins = NB;
  const int m0 = (bid - nbins) * 64;
  char* Al = lds;                      // 4 KB: [64 rows][32 k] bf16, swizzled
  char* Bl = lds + 64 * 64;            // 20 KB: [320 n][32 k] bf16, swizzled
  const int wid = t >> 6, lane = t & 63;
  const int wm = wid >> 2, wn = wid & 3;
  const int l15 = lane & 15, g = lane >> 4;

  f32x4 acc[2][5];
#pragma unroll
  for (int i = 0; i < 2; ++i)
#pragma unroll
    for (int j = 0; j < 5; ++j) acc[i][j] = (f32x4){0.f, 0.f, 0.f, 0.f};

  for (int kc = 0; kc < 8; ++kc) {
    const int k0 = kc * 32;
    if (kc) __syncthreads();
    // stage A: 64 rows x 32 k, f32 -> bf16 (one float4 per thread, exact)
    {
      int row = t >> 3, kq = (t & 7) * 4;
      int rg = m0 + row;
      float4 v = (rg < NN) ? *(const float4*)(x + (size_t)rg * 256 + k0 + kq)
                           : make_float4(0.f, 0.f, 0.f, 0.f);
      ushort4 pck = {f2bf(v.x), f2bf(v.y), f2bf(v.z), f2bf(v.w)};
      int wb = (row * 64 + kq * 2) ^ ((row & 7) << 4);
      *(ushort4*)(Al + wb) = pck;
    }
    // stage B: 320 n x 32 k bf16 = 1280 x 16B
#pragma unroll
    for (int it = 0; it < 3; ++it) {
      int fl = t + 512 * it;
      if (fl < 1280) {
        int n = fl >> 2, c = fl & 3;
        uint4 u = *(const uint4*)(BT1 + (size_t)n * 256 + k0 + c * 8);
        int wb = (n * 64 + c * 16) ^ ((n & 7) << 4);
        *(uint4*)(Bl + wb) = u;
      }
    }
    __syncthreads();
    bf16x8 af[2], bfr[5];
#pragma unroll
    for (int mi = 0; mi < 2; ++mi) {
      int row = wm * 32 + mi * 16 + l15;
      int byte = (row * 64 + g * 16) ^ ((row & 7) << 4);
      af[mi] = *(const bf16x8*)(Al + byte);
    }
#pragma unroll
    for (int ni = 0; ni < 5; ++ni) {
      int n = wn * 80 + ni * 16 + l15;
      int byte = (n * 64 + g * 16) ^ ((n & 7) << 4);
      bfr[ni] = *(const bf16x8*)(Bl + byte);
    }
#pragma unroll
    for (int mi = 0; mi < 2; ++mi)
#pragma unroll
      for (int ni = 0; ni < 5; ++ni)
        acc[mi][ni] = __builtin_amdgcn_mfma_f32_16x16x32_bf16(af[mi], bfr[ni], acc[mi][ni], 0, 0, 0);
  }
#pragma unroll
  for (int mi = 0; mi < 2; ++mi) {
    int rbase = m0 + wm * 32 + mi * 16 + 4 * g;
#pragma unroll
    for (int ni = 0; ni < 5; ++ni) {
      int n0 = wn * 80 + ni * 16;
      int n = n0 + l15;
#pragma unroll
      for (int e = 0; e < 4; ++e) {
        int row = rbase + e;
        if (row >= NN) continue;
        float v = acc[mi][ni][e];
        if (n0 < 256) hwcat[(size_t)row * 256 + n] = f2bf(v);
        else h[(size_t)row * 64 + (n - 256)] = f2bf(v + L1b[n - 256]);
      }
    }
  }
}

// ---- pull-L1 + gemm2: one block per bucket (64 nodes) ----
__global__ __launch_bounds__(256) void pull1_kernel(const unsigned short* __restrict__ h,
                                                    const unsigned short* __restrict__ hwcat,
                                                    const int* __restrict__ binned,
                                                    const int* __restrict__ gcur,
                                                    const unsigned short* __restrict__ BT2,
                                                    const float* __restrict__ L2b,
                                                    unsigned short* __restrict__ hw2,
                                                    float* __restrict__ out) {
  __shared__ int csr[BCAP];            // 12 KB; overlaid by Bl after gather
  __shared__ int cnt[256];
  __shared__ int off[256];
  __shared__ float winv[256];
  __shared__ int tot[64];
  __shared__ char Al[64 * 64 * 2];     // 8 KB bf16 A-tile (swizzled)
  const int t = threadIdx.x, bkt = blockIdx.x;
  const int wid = t >> 6, lane = t & 63;
  const int l15 = lane & 15, g = lane >> 4;

  int count = gcur[bkt];
  if (count > BCAP) count = BCAP;
  const int* edges = binned + (size_t)bkt * BCAP;

  cnt[t] = 0;
  __syncthreads();
  for (int i = t; i < count; i += 256) {
    int w = edges[i];
    atomicAdd(&cnt[((w >> 19) & 63) * 4 + (w & 3)], 1);
  }
  __syncthreads();
  off[t] = cnt[t];
  __syncthreads();
  for (int s = 1; s < 256; s <<= 1) {
    int v = (t >= s) ? off[t - s] : 0;
    __syncthreads();
    off[t] += v;
    __syncthreads();
  }
  int excl = off[t] - cnt[t];
  winv[t] = 1.0f / (float)(cnt[t] > 1 ? cnt[t] : 1);
  __syncthreads();
  off[t] = excl;
  cnt[t] = excl;                        // placement cursor
  __syncthreads();
  if (t < 64) tot[t] = ((t == 63) ? count : off[(t + 1) * 4]) - off[t * 4];
  __syncthreads();
  for (int i = t; i < count; i += 256) {
    int w = edges[i];
    int k = ((w >> 19) & 63) * 4 + (w & 3);
    int p = atomicAdd(&cnt[k], 1);
    csr[p] = w & 0x7FFFF;               // key = src*4+r
  }
  __syncthreads();

  // gather: wave wid handles nodes wid*16..+15; unified list, 8 slots x 16B
  const int slot = lane >> 3, cpart = lane & 7;
  for (int ii = 0; ii < 16; ++ii) {
    int nloc = wid * 16 + ii;
    int beg = off[nloc * 4];
    int total = tot[nloc];
    float acc[8] = {0.f, 0.f, 0.f, 0.f, 0.f, 0.f, 0.f, 0.f};
    for (int p0 = 0; p0 < total; p0 += 8) {
      int j = p0 + slot;
      bool pr = j < total;
      int key = pr ? csr[beg + j] : 0;
      float wv = pr ? winv[nloc * 4 + (key & 3)] : 0.f;
      uint4 u = *(const uint4*)(hwcat + (size_t)key * 64 + cpart * 8);
#pragma unroll
      for (int q = 0; q < 4; ++q) {
        unsigned uu = (&u.x)[q];
        acc[q * 2]     = fmaf(wv, bf2f((unsigned short)(uu & 0xffffu)), acc[q * 2]);
        acc[q * 2 + 1] = fmaf(wv, bf2f((unsigned short)(uu >> 16)), acc[q * 2 + 1]);
      }
    }
#pragma unroll
    for (int m = 8; m <= 32; m <<= 1)
#pragma unroll
      for (int q = 0; q < 8; ++q) acc[q] += __shfl_xor(acc[q], m);
    if (slot == 0) {  // lanes 0..7: self + relu + pack -> swizzled A-tile
      int gn = bkt * 64 + nloc;
      unsigned pk[4];
      uint4 hu = make_uint4(0, 0, 0, 0);
      if (gn < NN) hu = *(const uint4*)(h + (size_t)gn * 64 + cpart * 8);
#pragma unroll
      for (int q = 0; q < 4; ++q) {
        unsigned a = (&hu.x)[q];
        float v0 = acc[q * 2]     + bf2f((unsigned short)(a & 0xffffu));
        float v1 = acc[q * 2 + 1] + bf2f((unsigned short)(a >> 16));
        pk[q] = (unsigned)f2bf(fmaxf(v0, 0.f)) | ((unsigned)f2bf(fmaxf(v1, 0.f)) << 16);
      }
      int wb = ((nloc * 64 + cpart * 8) * 2) ^ ((nloc & 7) << 4);
      *(uint4*)(Al + wb) = make_uint4(pk[0], pk[1], pk[2], pk[3]);
    }
  }
  __syncthreads();

  // stage B over csr region: 80 x 64 bf16 = 640 uint4
  char* Bl = (char*)csr;
#pragma unroll
  for (int it = 0; it < 3; ++it) {
    int fl = t + 256 * it;
    if (fl < 640) {
      int n = fl >> 3, i8 = (fl & 7) * 8;
      uint4 u = *(const uint4*)(BT2 + (size_t)n * 64 + i8);
      int wb = ((n * 64 + i8) * 2) ^ ((n & 7) << 4);
      *(uint4*)(Bl + wb) = u;
    }
  }
  __syncthreads();

  // gemm2: wave wid -> rows wid*16..+15, N=80
  f32x4 acc2[5];
#pragma unroll
  for (int j = 0; j < 5; ++j) acc2[j] = (f32x4){0.f, 0.f, 0.f, 0.f};
#pragma unroll
  for (int ks = 0; ks < 2; ++ks) {
    int ra = wid * 16 + l15;
    int byte = ((ra * 64 + ks * 32 + g * 8) * 2) ^ ((ra & 7) << 4);
    bf16x8 af = *(const bf16x8*)(Al + byte);
#pragma unroll
    for (int ni = 0; ni < 5; ++ni) {
      int n = ni * 16 + l15;
      int nb = ((n * 64 + ks * 32 + g * 8) * 2) ^ ((n & 7) << 4);
      bf16x8 bfr = *(const bf16x8*)(Bl + nb);
      acc2[ni] = __builtin_amdgcn_mfma_f32_16x16x32_bf16(af, bfr, acc2[ni], 0, 0, 0);
    }
  }
  int rb = wid * 16 + 4 * g;
#pragma unroll
  for (int ni = 0; ni < 5; ++ni) {
    int n0 = ni * 16;
    int n = n0 + l15;
#pragma unroll
    for (int e = 0; e < 4; ++e) {
      int gno = bkt * 64 + rb + e;
      if (gno >= NN) continue;
      float vv = acc2[ni][e];
      if (n0 < 64) hw2[(size_t)gno * 64 + n] = f2bf(vv);
      else out[(size_t)gno * 16 + (n - 64)] = vv + L2b[n - 64];
    }
  }
}

// ---- pull-L2: rebuild LDS CSR (unified), gather hw2, accumulate out ----
__global__ __launch_bounds__(256) void pull2_kernel(const unsigned short* __restrict__ hw2,
                                                    const int* __restrict__ binned,
                                                    const int* __restrict__ gcur,
                                                    float* __restrict__ out) {
  __shared__ int csr[BCAP];
  __shared__ int cnt[256];
  __shared__ int off[256];
  __shared__ float winv[256];
  __shared__ int tot[64];
  __shared__ float ot[64][16];
  const int t = threadIdx.x, bkt = blockIdx.x;
  const int wid = t >> 6, lane = t & 63;

  int count = gcur[bkt];
  if (count > BCAP) count = BCAP;
  const int* edges = binned + (size_t)bkt * BCAP;

  cnt[t] = 0;
  __syncthreads();
  for (int i = t; i < count; i += 256) {
    int w = edges[i];
    atomicAdd(&cnt[((w >> 19) & 63) * 4 + (w & 3)], 1);
  }
  __syncthreads();
  off[t] = cnt[t];
  __syncthreads();
  for (int s = 1; s < 256; s <<= 1) {
    int v = (t >= s) ? off[t - s] : 0;
    __syncthreads();
    off[t] += v;
    __syncthreads();
  }
  int excl = off[t] - cnt[t];
  winv[t] = 1.0f / (float)(cnt[t] > 1 ? cnt[t] : 1);
  __syncthreads();
  off[t] = excl;
  cnt[t] = excl;
  __syncthreads();
  if (t < 64) tot[t] = ((t == 63) ? count : off[(t + 1) * 4]) - off[t * 4];
  __syncthreads();
  for (int i = t; i < count; i += 256) {
    int w = edges[i];
    int k = ((w >> 19) & 63) * 4 + (w & 3);
    int p = atomicAdd(&cnt[k], 1);
    csr[p] = w & 0x7FFFF;
  }
  __syncthreads();

  // gather: 16 slots x 4 cparts (8B); hw2 offset = key*16 + cpart*4
  const int slot = lane >> 2, cpart = lane & 3;
  for (int ii = 0; ii < 16; ++ii) {
    int nloc = wid * 16 + ii;
    int beg = off[nloc * 4];
    int total = tot[nloc];
    float acc[4] = {0.f, 0.f, 0.f, 0.f};
    for (int p0 = 0; p0 < total; p0 += 16) {
      int j = p0 + slot;
      bool pr = j < total;
      int key = pr ? csr[beg + j] : 0;
      float wv = pr ? winv[nloc * 4 + (key & 3)] : 0.f;
      uint2 u = *(const uint2*)(hw2 + (size_t)key * 16 + cpart * 4);
      acc[0] = fmaf(wv, bf2f((unsigned short)(u.x & 0xffffu)), acc[0]);
      acc[1] = fmaf(wv, bf2f((unsigned short)(u.x >> 16)), acc[1]);
      acc[2] = fmaf(wv, bf2f((unsigned short)(u.y & 0xffffu)), acc[2]);
      acc[3] = fmaf(wv, bf2f((unsigned short)(u.y >> 16)), acc[3]);
    }
#pragma unroll
    for (int m = 4; m <= 32; m <<= 1)
#pragma unroll
      for (int q = 0; q < 4; ++q) acc[q] += __shfl_xor(acc[q], m);
    if (slot == 0)
      *(float4*)&ot[nloc][cpart * 4] = make_float4(acc[0], acc[1], acc[2], acc[3]);
  }
  __syncthreads();

  int row = t >> 2, q = t & 3;
  int gn = bkt * 64 + row;
  if (gn < NN) {
    float4 o = *(float4*)(out + (size_t)gn * 16 + q * 4);
    float4 a = *(float4*)&ot[row][q * 4];
    o.x += a.x; o.y += a.y; o.z += a.z; o.w += a.w;
    *(float4*)(out + (size_t)gn * 16 + q * 4) = o;
  }
}

extern "C" void kernel_launch(void* const* d_in, const int* in_sizes, int n_in,
                              void* d_out, int out_size, void* d_ws, size_t ws_size,
                              hipStream_t stream) {
  const float* x   = (const float*)d_in[0];
  const int*   src = (const int*)d_in[1];
  const int*   dst = (const int*)d_in[2];
  const float* W1  = (const float*)d_in[3];
  const float* L1w = (const float*)d_in[4];
  const float* L1b = (const float*)d_in[5];
  const float* W2  = (const float*)d_in[6];
  const float* L2w = (const float*)d_in[7];
  const float* L2b = (const float*)d_in[8];
  float* out = (float*)d_out;

  char* p = (char*)d_ws;
  int* binned = (int*)p;                      p += (size_t)NBKT * BCAP * 4;   // 19.2 MB
  int* gcur   = (int*)p;                      p += 8192;
  unsigned short* hwcat = (unsigned short*)p; p += (size_t)NN * 256 * 2;      // 51.2 MB
  unsigned short* h = (unsigned short*)p;     p += (size_t)NN * 64 * 2;       // 12.8 MB
  unsigned short* hw2 = (unsigned short*)p;   p += (size_t)NN * 64 * 2;       // 12.8 MB
  unsigned short* BT1 = (unsigned short*)p;   p += 320 * 256 * 2;
  unsigned short* BT2 = (unsigned short*)p;   p += 80 * 64 * 2;
  if ((size_t)(p - (char*)d_ws) > ws_size) return;  // visible fail (poison stays)

  hipMemsetAsync(gcur, 0, NBKT * 4, stream);
  prep_w_kernel<<<(320 * 256 + 80 * 64 + 255) / 256, 256, 0, stream>>>(W1, L1w, W2, L2w, BT1, BT2);
  fused1_kernel<<<NG1 + NB, 512, 0, stream>>>(x, BT1, L1b, src, dst, gcur, binned, hwcat, h);
  pull1_kernel<<<NBKT, 256, 0, stream>>>(h, hwcat, binned, gcur, BT2, L2b, hw2, out);
  pull2_kernel<<<NBKT, 256, 0, stream>>>(hw2, binned, gcur, out);
}

// Round 15
// 235.519 us; speedup vs baseline: 1.0018x; 1.0018x over previous
//
#include <hip/hip_runtime.h>

// EntityClassify (R-GCN) — round 15.
// r14 post-mortem: BK=32 REGRESSED (bank conflicts 753k->3.55M, occupancy
// unmoved -> staging latency, not LDS cap, is the limiter). Reverted to BK=64.
// This round: (1) B-tile staged via global_load_lds from PRE-SWIZZLED BT1sw
// (prep_w stores each 16B group at its swizzled offset; LDS write is linear,
// swizzle comes from the source permutation) — no VGPR round-trip; (2) A-reg
// prefetch issued right AFTER the stage barrier so x HBM latency drains under
// MFMA; (3) pull1 writes built CSR + (off|tot) headers + winv to global ->
// pull2 build collapses to a coalesced copy; pull1 scan -> wave shfl_up scan.

constexpr int NN = 100000, RR = 4, EE = 800000;
constexpr int RE = RR * EE;
constexpr int NBKT = (NN + 63) / 64;      // 1563 buckets of 64 dst nodes
constexpr int BCAP = 3072;                // per-bucket capacity (λ≈2046)
constexpr int NG1 = (NN + 63) / 64;       // 1563 gemm1 tiles (M=64)
constexpr int CHUNK = 8192;
constexpr int NB = (RE + CHUNK - 1) / CHUNK;  // 391 bin blocks
constexpr int EPT = CHUNK / 512;          // 16 edges per thread

typedef short bf16x8 __attribute__((ext_vector_type(8)));
typedef float f32x4 __attribute__((ext_vector_type(4)));

__device__ inline unsigned short f2bf(float f) {
  unsigned u = __float_as_uint(f);
  u += 0x7FFF + ((u >> 16) & 1);
  return (unsigned short)(u >> 16);
}
__device__ inline float bf2f(unsigned short s) {
  return __uint_as_float(((unsigned)s) << 16);
}

// ---- weights: BT1sw = pre-swizzled per-K-chunk [4][40960B]; BT2 [80][64] ----
__global__ __launch_bounds__(256) void prep_w_kernel(const float* __restrict__ W1,
                                                     const float* __restrict__ L1w,
                                                     const float* __restrict__ W2,
                                                     const float* __restrict__ L2w,
                                                     unsigned short* __restrict__ BT1sw,
                                                     unsigned short* __restrict__ BT2) {
  int idx = blockIdx.x * 256 + threadIdx.x;
  if (idx < 320 * 256) {
    int n = idx >> 8, k = idx & 255;
    float v = (n < 256) ? W1[((size_t)((n >> 6) * 256 + k)) * 64 + (n & 63)]
                        : L1w[(size_t)k * 64 + (n - 256)];
    // swizzled position: chunk kc, 8-elem group c, elem e
    int kc = k >> 6, c = (k & 63) >> 3, e = k & 7;
    int byteoff = kc * 40960 + ((n * 128 + c * 16) ^ ((n & 7) << 4)) + e * 2;
    *(unsigned short*)((char*)BT1sw + byteoff) = f2bf(v);
  } else {
    int j = idx - 320 * 256;
    if (j < 80 * 64) {
      int n = j >> 6, k = j & 63;
      float v = (n < 64) ? W2[((size_t)((n >> 4) * 64 + k)) * 16 + (n & 15)]
                         : L2w[(size_t)k * 16 + (n - 64)];
      BT2[j] = f2bf(v);
    }
  }
}

// ---- fused1: bin blocks (every 5th) ∥ gemm1 blocks (BK=64, 48KB LDS) ----
__global__ __launch_bounds__(512) void fused1_kernel(const float* __restrict__ x,
                                                     const unsigned short* __restrict__ BT1sw,
                                                     const float* __restrict__ L1b,
                                                     const int* __restrict__ src,
                                                     const int* __restrict__ dst,
                                                     int* __restrict__ gcur,
                                                     int* __restrict__ binned,
                                                     unsigned short* __restrict__ hwcat,
                                                     unsigned short* __restrict__ h) {
  __shared__ char lds[49152];
  const int bid = blockIdx.x;
  const int t = threadIdx.x;
  const bool is_bin = (bid % 5 == 0) && (bid / 5 < NB);

  if (is_bin) {
    int* hist = (int*)lds;          // [NBKT]
    int* base = hist + NBKT;        // [NBKT]
    for (int k = t; k < NBKT; k += 512) hist[k] = 0;
    __syncthreads();
    const int e0 = (bid / 5) * CHUNK + t;
    int dl[EPT], sl[EPT];
#pragma unroll
    for (int i = 0; i < EPT; ++i) {
      int fl = e0 + i * 512;
      dl[i] = -1;
      if (fl < RE) {
        dl[i] = dst[fl];
        sl[i] = src[fl];
        atomicAdd(&hist[dl[i] >> 6], 1);
      }
    }
    __syncthreads();
    for (int k = t; k < NBKT; k += 512) {
      int hv = hist[k];
      base[k] = hv ? atomicAdd(&gcur[k], hv) : 0;
      hist[k] = 0;
    }
    __syncthreads();
#pragma unroll
    for (int i = 0; i < EPT; ++i) {
      if (dl[i] < 0) continue;
      int fl = e0 + i * 512;
      int r = fl / EE;
      int b = dl[i] >> 6;
      int off = atomicAdd(&hist[b], 1);
      int p = base[b] + off;
      if (p < BCAP) binned[(size_t)b * BCAP + p] = (sl[i] << 2) | r | ((dl[i] & 63) << 19);
    }
    return;
  }

  // ---- gemm1 role: M-tile 64, N=320, K=256, BK=64 ----
  int nbins = (bid + 4) / 5;
  if (nbins > NB) nbins = NB;
  const int m0 = (bid - nbins) * 64;
  char* Al = lds;                      // 8 KB
  char* Bl = lds + 8192;               // 40 KB
  const int wid = t >> 6, lane = t & 63;
  const int wm = wid >> 2, wn = wid & 3;
  const int l15 = lane & 15, g = lane >> 4;

  f32x4 acc[2][5];
#pragma unroll
  for (int i = 0; i < 2; ++i)
#pragma unroll
    for (int j = 0; j < 5; ++j) acc[i][j] = (f32x4){0.f, 0.f, 0.f, 0.f};

  const int row0 = t >> 4, kq0 = (t & 15) * 4;
  const int row1 = (t + 512) >> 4, kq1 = ((t + 512) & 15) * 4;
  const int rg0 = m0 + row0, rg1 = m0 + row1;
  const float4 z4 = make_float4(0.f, 0.f, 0.f, 0.f);

  float4 a0 = (rg0 < NN) ? *(const float4*)(x + (size_t)rg0 * 256 + kq0) : z4;
  float4 a1 = (rg1 < NN) ? *(const float4*)(x + (size_t)rg1 * 256 + kq1) : z4;

  for (int kc = 0; kc < 4; ++kc) {
    if (kc) __syncthreads();
    // B: direct-to-LDS from pre-swizzled source (linear dest, swz from src)
    {
      const char* gB = (const char*)BT1sw + kc * 40960;
#pragma unroll
      for (int it = 0; it < 5; ++it) {
        int sl5 = (it * 8 + wid) * 1024;
        __builtin_amdgcn_global_load_lds((const unsigned int*)(gB + sl5 + lane * 16),
                                         (unsigned int*)(Bl + sl5), 16, 0, 0);
      }
    }
    // A: regs -> bf16 -> swizzled LDS
    {
      ushort4 p0 = {f2bf(a0.x), f2bf(a0.y), f2bf(a0.z), f2bf(a0.w)};
      int wb0 = ((row0 * 64 + kq0) * 2) ^ ((row0 & 7) << 4);
      *(ushort4*)(Al + wb0) = p0;
      ushort4 p1 = {f2bf(a1.x), f2bf(a1.y), f2bf(a1.z), f2bf(a1.w)};
      int wb1 = ((row1 * 64 + kq1) * 2) ^ ((row1 & 7) << 4);
      *(ushort4*)(Al + wb1) = p1;
    }
    __syncthreads();
    if (kc < 3) {  // prefetch next A chunk: latency drains under MFMA below
      a0 = (rg0 < NN) ? *(const float4*)(x + (size_t)rg0 * 256 + (kc + 1) * 64 + kq0) : z4;
      a1 = (rg1 < NN) ? *(const float4*)(x + (size_t)rg1 * 256 + (kc + 1) * 64 + kq1) : z4;
    }
#pragma unroll
    for (int ks = 0; ks < 2; ++ks) {
      bf16x8 af[2], bfr[5];
#pragma unroll
      for (int mi = 0; mi < 2; ++mi) {
        int row = wm * 32 + mi * 16 + l15;
        int byte = ((row * 64 + ks * 32 + g * 8) * 2) ^ ((row & 7) << 4);
        af[mi] = *(const bf16x8*)(Al + byte);
      }
#pragma unroll
      for (int ni = 0; ni < 5; ++ni) {
        int n = wn * 80 + ni * 16 + l15;
        int byte = ((n * 64 + ks * 32 + g * 8) * 2) ^ ((n & 7) << 4);
        bfr[ni] = *(const bf16x8*)(Bl + byte);
      }
#pragma unroll
      for (int mi = 0; mi < 2; ++mi)
#pragma unroll
        for (int ni = 0; ni < 5; ++ni)
          acc[mi][ni] = __builtin_amdgcn_mfma_f32_16x16x32_bf16(af[mi], bfr[ni], acc[mi][ni], 0, 0, 0);
    }
  }
#pragma unroll
  for (int mi = 0; mi < 2; ++mi) {
    int rbase = m0 + wm * 32 + mi * 16 + 4 * g;
#pragma unroll
    for (int ni = 0; ni < 5; ++ni) {
      int n0 = wn * 80 + ni * 16;
      int n = n0 + l15;
#pragma unroll
      for (int e = 0; e < 4; ++e) {
        int row = rbase + e;
        if (row >= NN) continue;
        float v = acc[mi][ni][e];
        if (n0 < 256) hwcat[(size_t)row * 256 + n] = f2bf(v);
        else h[(size_t)row * 64 + (n - 256)] = f2bf(v + L1b[n - 256]);
      }
    }
  }
}

// ---- pull-L1 + gemm2: one block per bucket; writes CSR+headers for pull2 ----
__global__ __launch_bounds__(256) void pull1_kernel(const unsigned short* __restrict__ h,
                                                    const unsigned short* __restrict__ hwcat,
                                                    int* __restrict__ binned,
                                                    const int* __restrict__ gcur,
                                                    const unsigned short* __restrict__ BT2,
                                                    const float* __restrict__ L2b,
                                                    unsigned* __restrict__ hdrG,
                                                    float* __restrict__ winvG,
                                                    unsigned short* __restrict__ hw2,
                                                    float* __restrict__ out) {
  __shared__ int csr[BCAP];            // 12 KB; overlaid by Bl after gather
  __shared__ int cnt[256];
  __shared__ int off[256];
  __shared__ float winv[256];
  __shared__ int tot[64];
  __shared__ int wsum[4];
  __shared__ char Al[64 * 64 * 2];     // 8 KB bf16 A-tile (swizzled)
  const int t = threadIdx.x, bkt = blockIdx.x;
  const int wid = t >> 6, lane = t & 63;
  const int l15 = lane & 15, g = lane >> 4;

  int count = gcur[bkt];
  if (count > BCAP) count = BCAP;
  const int* edges = binned + (size_t)bkt * BCAP;

  // histogram by (node,rel)
  cnt[t] = 0;
  __syncthreads();
  for (int i = t; i < count; i += 256) {
    int w = edges[i];
    atomicAdd(&cnt[((w >> 19) & 63) * 4 + (w & 3)], 1);
  }
  __syncthreads();
  // wave shfl_up scan (2 barriers instead of 16)
  int v = cnt[t];
  int xs = v;
#pragma unroll
  for (int d = 1; d < 64; d <<= 1) {
    int y = __shfl_up(xs, d);
    if (lane >= d) xs += y;
  }
  if (lane == 63) wsum[wid] = xs;
  __syncthreads();
  int add = 0;
#pragma unroll
  for (int w2 = 0; w2 < 4; ++w2)
    if (w2 < wid) add += wsum[w2];
  int excl = xs + add - v;
  winv[t] = 1.0f / (float)(v > 1 ? v : 1);
  off[t] = excl;
  cnt[t] = excl;                        // placement cursor
  __syncthreads();
  if (t < 64) tot[t] = ((t == 63) ? count : off[(t + 1) * 4]) - off[t * 4];
  for (int i = t; i < count; i += 256) {
    int w = edges[i];
    int k = ((w >> 19) & 63) * 4 + (w & 3);
    int p = atomicAdd(&cnt[k], 1);
    csr[p] = w & 0x7FFFF;               // key = src*4+r
  }
  __syncthreads();

  // hand off built CSR to pull2 (coalesced), plus headers + winv
  for (int i = t; i < count; i += 256) binned[(size_t)bkt * BCAP + i] = csr[i];
  winvG[bkt * 256 + t] = winv[t];
  if (t < 64) hdrG[bkt * 64 + t] = (unsigned)off[t * 4] | ((unsigned)tot[t] << 16);

  // gather: wave wid -> nodes wid*16..+15; unified list, 8 slots x 16B
  const int slot = lane >> 3, cpart = lane & 7;
  for (int ii = 0; ii < 16; ++ii) {
    int nloc = wid * 16 + ii;
    int beg = off[nloc * 4];
    int total = tot[nloc];
    float acc[8] = {0.f, 0.f, 0.f, 0.f, 0.f, 0.f, 0.f, 0.f};
    for (int p0 = 0; p0 < total; p0 += 8) {
      int j = p0 + slot;
      bool pr = j < total;
      int key = pr ? csr[beg + j] : 0;
      float wv = pr ? winv[nloc * 4 + (key & 3)] : 0.f;
      uint4 u = *(const uint4*)(hwcat + (size_t)key * 64 + cpart * 8);
#pragma unroll
      for (int q = 0; q < 4; ++q) {
        unsigned uu = (&u.x)[q];
        acc[q * 2]     = fmaf(wv, bf2f((unsigned short)(uu & 0xffffu)), acc[q * 2]);
        acc[q * 2 + 1] = fmaf(wv, bf2f((unsigned short)(uu >> 16)), acc[q * 2 + 1]);
      }
    }
#pragma unroll
    for (int m = 8; m <= 32; m <<= 1)
#pragma unroll
      for (int q = 0; q < 8; ++q) acc[q] += __shfl_xor(acc[q], m);
    if (slot == 0) {  // lanes 0..7: self + relu + pack -> swizzled A-tile
      int gn = bkt * 64 + nloc;
      unsigned pk[4];
      uint4 hu = make_uint4(0, 0, 0, 0);
      if (gn < NN) hu = *(const uint4*)(h + (size_t)gn * 64 + cpart * 8);
#pragma unroll
      for (int q = 0; q < 4; ++q) {
        unsigned a = (&hu.x)[q];
        float v0 = acc[q * 2]     + bf2f((unsigned short)(a & 0xffffu));
        float v1 = acc[q * 2 + 1] + bf2f((unsigned short)(a >> 16));
        pk[q] = (unsigned)f2bf(fmaxf(v0, 0.f)) | ((unsigned)f2bf(fmaxf(v1, 0.f)) << 16);
      }
      int wb = ((nloc * 64 + cpart * 8) * 2) ^ ((nloc & 7) << 4);
      *(uint4*)(Al + wb) = make_uint4(pk[0], pk[1], pk[2], pk[3]);
    }
  }
  __syncthreads();

  // stage B over csr region
  char* Bl = (char*)csr;
#pragma unroll
  for (int it = 0; it < 3; ++it) {
    int fl = t + 256 * it;
    if (fl < 640) {
      int n = fl >> 3, i8 = (fl & 7) * 8;
      uint4 u = *(const uint4*)(BT2 + (size_t)n * 64 + i8);
      int wb = ((n * 64 + i8) * 2) ^ ((n & 7) << 4);
      *(uint4*)(Bl + wb) = u;
    }
  }
  __syncthreads();

  // gemm2: wave wid -> rows wid*16..+15, N=80
  f32x4 acc2[5];
#pragma unroll
  for (int j = 0; j < 5; ++j) acc2[j] = (f32x4){0.f, 0.f, 0.f, 0.f};
#pragma unroll
  for (int ks = 0; ks < 2; ++ks) {
    int ra = wid * 16 + l15;
    int byte = ((ra * 64 + ks * 32 + g * 8) * 2) ^ ((ra & 7) << 4);
    bf16x8 af = *(const bf16x8*)(Al + byte);
#pragma unroll
    for (int ni = 0; ni < 5; ++ni) {
      int n = ni * 16 + l15;
      int nb = ((n * 64 + ks * 32 + g * 8) * 2) ^ ((n & 7) << 4);
      bf16x8 bfr = *(const bf16x8*)(Bl + nb);
      acc2[ni] = __builtin_amdgcn_mfma_f32_16x16x32_bf16(af, bfr, acc2[ni], 0, 0, 0);
    }
  }
  int rb = wid * 16 + 4 * g;
#pragma unroll
  for (int ni = 0; ni < 5; ++ni) {
    int n0 = ni * 16;
    int n = n0 + l15;
#pragma unroll
    for (int e = 0; e < 4; ++e) {
      int gno = bkt * 64 + rb + e;
      if (gno >= NN) continue;
      float vv = acc2[ni][e];
      if (n0 < 64) hw2[(size_t)gno * 64 + n] = f2bf(vv);
      else out[(size_t)gno * 16 + (n - 64)] = vv + L2b[n - 64];
    }
  }
}

// ---- pull-L2: copy prebuilt CSR, gather hw2, accumulate out ----
__global__ __launch_bounds__(256) void pull2_kernel(const unsigned short* __restrict__ hw2,
                                                    const int* __restrict__ binned,
                                                    const int* __restrict__ gcur,
                                                    const unsigned* __restrict__ hdrG,
                                                    const float* __restrict__ winvG,
                                                    float* __restrict__ out) {
  __shared__ int csr[BCAP];
  __shared__ float winvL[256];
  __shared__ int begL[64], totL[64];
  __shared__ float ot[64][16];
  const int t = threadIdx.x, bkt = blockIdx.x;
  const int wid = t >> 6, lane = t & 63;

  int count = gcur[bkt];
  if (count > BCAP) count = BCAP;
  for (int i = t; i < count; i += 256) csr[i] = binned[(size_t)bkt * BCAP + i];
  winvL[t] = winvG[bkt * 256 + t];
  if (t < 64) {
    unsigned hd = hdrG[bkt * 64 + t];
    begL[t] = hd & 0xffff;
    totL[t] = hd >> 16;
  }
  __syncthreads();

  // gather: 16 slots x 4 cparts (8B); hw2 offset = key*16 + cpart*4
  const int slot = lane >> 2, cpart = lane & 3;
  for (int ii = 0; ii < 16; ++ii) {
    int nloc = wid * 16 + ii;
    int beg = begL[nloc];
    int total = totL[nloc];
    float acc[4] = {0.f, 0.f, 0.f, 0.f};
    for (int p0 = 0; p0 < total; p0 += 16) {
      int j = p0 + slot;
      bool pr = j < total;
      int key = pr ? csr[beg + j] : 0;
      float wv = pr ? winvL[nloc * 4 + (key & 3)] : 0.f;
      uint2 u = *(const uint2*)(hw2 + (size_t)key * 16 + cpart * 4);
      acc[0] = fmaf(wv, bf2f((unsigned short)(u.x & 0xffffu)), acc[0]);
      acc[1] = fmaf(wv, bf2f((unsigned short)(u.x >> 16)), acc[1]);
      acc[2] = fmaf(wv, bf2f((unsigned short)(u.y & 0xffffu)), acc[2]);
      acc[3] = fmaf(wv, bf2f((unsigned short)(u.y >> 16)), acc[3]);
    }
#pragma unroll
    for (int m = 4; m <= 32; m <<= 1)
#pragma unroll
      for (int q = 0; q < 4; ++q) acc[q] += __shfl_xor(acc[q], m);
    if (slot == 0)
      *(float4*)&ot[nloc][cpart * 4] = make_float4(acc[0], acc[1], acc[2], acc[3]);
  }
  __syncthreads();

  int row = t >> 2, q = t & 3;
  int gn = bkt * 64 + row;
  if (gn < NN) {
    float4 o = *(float4*)(out + (size_t)gn * 16 + q * 4);
    float4 a = *(float4*)&ot[row][q * 4];
    o.x += a.x; o.y += a.y; o.z += a.z; o.w += a.w;
    *(float4*)(out + (size_t)gn * 16 + q * 4) = o;
  }
}

extern "C" void kernel_launch(void* const* d_in, const int* in_sizes, int n_in,
                              void* d_out, int out_size, void* d_ws, size_t ws_size,
                              hipStream_t stream) {
  const float* x   = (const float*)d_in[0];
  const int*   src = (const int*)d_in[1];
  const int*   dst = (const int*)d_in[2];
  const float* W1  = (const float*)d_in[3];
  const float* L1w = (const float*)d_in[4];
  const float* L1b = (const float*)d_in[5];
  const float* W2  = (const float*)d_in[6];
  const float* L2w = (const float*)d_in[7];
  const float* L2b = (const float*)d_in[8];
  float* out = (float*)d_out;

  char* p = (char*)d_ws;
  int* binned = (int*)p;                      p += (size_t)NBKT * BCAP * 4;   // 19.2 MB
  int* gcur   = (int*)p;                      p += 8192;
  unsigned short* hwcat = (unsigned short*)p; p += (size_t)NN * 256 * 2;      // 51.2 MB
  unsigned short* h = (unsigned short*)p;     p += (size_t)NN * 64 * 2;       // 12.8 MB
  unsigned short* hw2 = (unsigned short*)p;   p += (size_t)NN * 64 * 2;       // 12.8 MB
  unsigned short* BT1sw = (unsigned short*)p; p += 4 * 40960;                 // 160 KB
  unsigned short* BT2 = (unsigned short*)p;   p += 80 * 64 * 2;
  unsigned* hdrG = (unsigned*)p;              p += (size_t)NBKT * 64 * 4;     // 400 KB
  float* winvG = (float*)p;                   p += (size_t)NBKT * 256 * 4;    // 1.6 MB
  if ((size_t)(p - (char*)d_ws) > ws_size) return;  // visible fail (poison stays)

  hipMemsetAsync(gcur, 0, NBKT * 4, stream);
  prep_w_kernel<<<(320 * 256 + 80 * 64 + 255) / 256, 256, 0, stream>>>(W1, L1w, W2, L2w, BT1sw, BT2);
  fused1_kernel<<<NG1 + NB, 512, 0, stream>>>(x, BT1sw, L1b, src, dst, gcur, binned, hwcat, h);
  pull1_kernel<<<NBKT, 256, 0, stream>>>(h, hwcat, binned, gcur, BT2, L2b, hdrG, winvG, hw2, out);
  pull2_kernel<<<NBKT, 256, 0, stream>>>(hw2, binned, gcur, hdrG, winvG, out);
}